// Round 6
// baseline (2223.663 us; speedup 1.0000x reference)
//
#include <hip/hip_runtime.h>
#include <stdint.h>

// MarkovChain FFBS: B=64, T=1024, K=512, I=4
// R17 = R16 with {3x power_gemm, sort, backward} FUSED into one dispatch
// (3 dispatches total: memset, setup_all, fused_main). Motivation: R16's
// non-backward 124us is mostly stream/graph serialization of stages most
// backward work doesn't need (75% of runs need only P/P^2).
//   - fused_main: 2048 blocks x 256thr = exactly 8 blocks/CU, co-resident
//     by construction (__launch_bounds__(256,8) caps VGPR 64; LDS 16.9KB).
//     Spin-gating is deadlock-free only because grid == capacity.
//   - blocks 0..543: GEMM stages (1 tile/block/stage), sequenced via
//     stagesDone flag (agent-scope release/acquire; ONE RMW per block per
//     stage -- no atomic storms). blocks 544..672: LDS-staged sort.
//     All blocks then run backward; remap puts producer blocks on the
//     shortest units.
//   - per-unit power gating: need = f(min(len,lmax)); not-ready units
//     deferred via skip bitmask (no head-of-line blocking), revisited.
//   - zigzag strided rank assignment (better wave-sum balance than stride).
// Per-k backward values bit-identical to R11..R16 -> absmax 0.

#define JAX_PARTITIONABLE 1

#define B_ 64
#define T_ 1024
#define K_ 512
#define I_ 4
#define NCHAIN (B_ * I_)
#define POWSLOT (513 * 512)   // rows 0..511 = P^L, row 512 = init_p @ P^L
#define LMAX_WANT 6
#define MAXRUNS 32769
#define MEGA_BLOCKS 2048
#define NWAVES (MEGA_BLOCKS * 4)
#define GEMM_TILES 272        // 17*16 tiles of 32x32 covering 513x512
#define SORT_BLOCKS 129       // ceil(MAXRUNS / 256)
#define SORT_BASE 544

typedef double f64x4 __attribute__((ext_vector_type(4)));

// ---------------- scoped atomic helpers ----------------
__device__ inline int ld_acq(const int* p) {
  return __hip_atomic_load(p, __ATOMIC_ACQUIRE, __HIP_MEMORY_SCOPE_AGENT);
}
__device__ inline void st_rel(int* p, int v) {
  __hip_atomic_store(p, v, __ATOMIC_RELEASE, __HIP_MEMORY_SCOPE_AGENT);
}
__device__ inline int add_arl(int* p, int v) {
  return __hip_atomic_fetch_add(p, v, __ATOMIC_ACQ_REL, __HIP_MEMORY_SCOPE_AGENT);
}

// ---------------- Threefry-2x32-20 (exact jax semantics) ----------------
__host__ __device__ inline void tf2x32(uint32_t k0, uint32_t k1, uint32_t c0, uint32_t c1,
                                       uint32_t& o0, uint32_t& o1) {
  uint32_t ks2 = k0 ^ k1 ^ 0x1BD11BDAu;
  uint32_t x0 = c0 + k0;
  uint32_t x1 = c1 + k1;
#define TFR(r) { x0 += x1; x1 = (x1 << (r)) | (x1 >> (32 - (r))); x1 ^= x0; }
  TFR(13) TFR(15) TFR(26) TFR(6)
  x0 += k1; x1 += ks2 + 1u;
  TFR(17) TFR(29) TFR(16) TFR(24)
  x0 += ks2; x1 += k0 + 2u;
  TFR(13) TFR(15) TFR(26) TFR(6)
  x0 += k0; x1 += k1 + 3u;
  TFR(17) TFR(29) TFR(16) TFR(24)
  x0 += k1; x1 += ks2 + 4u;
  TFR(13) TFR(15) TFR(26) TFR(6)
  x0 += ks2; x1 += k0 + 5u;
#undef TFR
  o0 = x0; o1 = x1;
}

__device__ inline uint32_t rng_bits(uint32_t kj0, uint32_t kj1, uint32_t e) {
#if JAX_PARTITIONABLE
  uint32_t a, b;
  tf2x32(kj0, kj1, 0u, e, a, b);
  return a ^ b;
#else
  const uint32_t HALF = (uint32_t)(NCHAIN * K_ / 2);
  uint32_t a, b;
  if (e < HALF) { tf2x32(kj0, kj1, e, e + HALF, a, b); return a; }
  else          { tf2x32(kj0, kj1, e - HALF, e, a, b); return b; }
#endif
}

// gumbel scale factor: G = -1/log(u) > 0, so that w*G is a monotone image of
// log(w) + (-log(-log u)). Branch-free log, <=2ulp RELATIVE everywhere.
__device__ inline float gumbel_scale(uint32_t bits) {
  float f = __uint_as_float((bits >> 9) | 0x3F800000u) - 1.0f;
  float u = f + 1.17549435e-38f;            // u in [2^-126, 1)
  int iu = __float_as_int(u);
  float ef = (float)((iu >> 23) - 127);
  float m = __int_as_float((iu & 0x007fffff) | 0x3f800000);   // [1,2)
  int big = m > 1.41421356f;                // reduce to [~0.707, ~1.414)
  m = big ? m * 0.5f : m;
  ef = big ? ef + 1.0f : ef;
  float fm = m - 1.0f;                      // exact (Sterbenz)
  float r = fm * __builtin_amdgcn_rcpf(m + 1.0f);   // atanh arg, |r|<=0.172
  float r2 = r * r;
  float p = fmaf(r2, fmaf(r2, fmaf(r2, fmaf(r2, 0.11111111f, 0.14285715f),
                                   0.2f), 0.33333334f), 1.0f);
  float logu = fmaf(ef, 0.69314718f, (r + r) * p);  // < 0 strictly
  return -__builtin_amdgcn_rcpf(logu);
}

__device__ inline void step_key(uint32_t ks0, uint32_t ks1, int j, uint32_t& kj0, uint32_t& kj1) {
#if JAX_PARTITIONABLE
  tf2x32(ks0, ks1, 0u, (uint32_t)j, kj0, kj1);
#else
  const int N = T_ - 1;
  uint32_t o0, o1;
  int v = 2 * j;
  if (v < N) { tf2x32(ks0, ks1, (uint32_t)v, (uint32_t)(v + N), o0, o1); kj0 = o0; }
  else       { tf2x32(ks0, ks1, (uint32_t)(v - N), (uint32_t)v, o0, o1); kj0 = o1; }
  v = 2 * j + 1;
  if (v < N) { tf2x32(ks0, ks1, (uint32_t)v, (uint32_t)(v + N), o0, o1); kj1 = o0; }
  else       { tf2x32(ks0, ks1, (uint32_t)(v - N), (uint32_t)v, o0, o1); kj1 = o1; }
#endif
}

// ---------------- Merged setup: offsets scan + transpose + V1 + keys ----------------
// Header pre-zeroed via hipMemsetAsync.
// blocks 0..63   : per-b offsets scan, run extraction (LDS-aggregated hist/maxL)
// blocks 64..127 : 64x64 LDS-tiled transpose P -> PTp(+1/K), POW0 copy (same load)
// block 128      : V1 = initp @ P (f64, split-K over 2 halves) + INITROW copy
// block 129      : step keys
__global__ __launch_bounds__(1024) void setup_all(
    const int* __restrict__ data, const float* __restrict__ masks,
    const float* __restrict__ P, const float* __restrict__ initp,
    float* __restrict__ POW0, float* __restrict__ PTp,
    float* __restrict__ INITROW, float* __restrict__ V1,
    int* __restrict__ off, int lmax, int initoff,
    int* __restrict__ runs, int* __restrict__ runCount, int* __restrict__ maxLdev,
    int* __restrict__ hist,
    uint32_t* __restrict__ KEY0, uint32_t* __restrict__ KEY1,
    uint32_t ks0, uint32_t ks1) {
  int blk = blockIdx.x;
  int tid = threadIdx.x;
  if (blk < 64) {
    __shared__ int prevObs[1024];
    __shared__ int nextObs[1024];
    __shared__ int lhist[64];
    __shared__ int lmaxL;
    int b = blk;
    int t = tid;
    bool obs = masks[b * T_ + t] > 0.0f;
    prevObs[t] = obs ? t : -1;
    nextObs[t] = obs ? t : T_;
    if (t < 64) lhist[t] = 0;
    if (t == 0) lmaxL = 1;
    __syncthreads();
    for (int o = 1; o < 1024; o <<= 1) {
      int pv = (t >= o) ? prevObs[t - o] : -1;
      int nv = (t + o < 1024) ? nextObs[t + o] : T_;
      __syncthreads();
      if (pv > prevObs[t]) prevObs[t] = pv;
      if (nv < nextObs[t]) nextObs[t] = nv;
      __syncthreads();
    }
    int t0 = (t > 0) ? prevObs[t - 1] : -1;
    int idx = b * T_ + t;
    if (obs) off[idx] = -1;
    else if (t0 >= 0) {
      int L = t - t0; if (L > lmax) L = lmax;
      off[idx] = (L - 1) * POWSLOT + data[b * T_ + t0] * 512;
    } else if (t == 0) off[idx] = initoff;
    else {
      int L = t; if (L > lmax) L = lmax;
      off[idx] = (L - 1) * POWSLOT + 512 * 512;   // init-chain V row
    }
    if (!obs && t <= T_ - 2 && (t == 0 || masks[b * T_ + t - 1] > 0.0f)) {
      int te = nextObs[t] - 1; if (te > T_ - 2) te = T_ - 2;
      int r = atomicAdd(runCount, 1);   // uniform addr, +1 -> wave-coalesced
      if (r < MAXRUNS) {
        runs[r] = (b << 20) | (t << 10) | te;
        int steps = te - t + 1;
        int bkt = steps < 63 ? steps : 63;
        atomicAdd(&lhist[bkt], 1);                 // LDS atomic
        int maxL = (t == 0) ? te : (te - t + 1);
        if (maxL > 1) atomicMax(&lmaxL, maxL);     // LDS atomic
      }
    }
    __syncthreads();
    if (t < 64) {
      int c = lhist[t];
      if (c) atomicAdd(&hist[t], c);               // 64 distinct addresses
    }
    if (t == 0) {
      int v = lmaxL;
      if (v > 1) atomicMax(maxLdev, v);            // one per block
    }
  } else if (blk < 128) {
    // 64x64 tile transpose, both sides coalesced; POW0 copy reuses the load.
    __shared__ float Tls[64][65];
    int tt = blk - 64, tr = tt >> 3, tc = tt & 7;
    int r = tid >> 4, c4 = (tid & 15) << 2;
    int src = ((tr << 6) + r) * 512 + (tc << 6) + c4;
    float4 v = *(const float4*)(P + src);
    *(float4*)(POW0 + src) = v;
    Tls[c4 + 0][r] = v.x;
    Tls[c4 + 1][r] = v.y;
    Tls[c4 + 2][r] = v.z;
    Tls[c4 + 3][r] = v.w;
    __syncthreads();
    const float q = 0.001953125f;   // + 1/K, bit-identical to inline add
    float4 w;
    w.x = Tls[r][c4 + 0] + q;
    w.y = Tls[r][c4 + 1] + q;
    w.z = Tls[r][c4 + 2] + q;
    w.w = Tls[r][c4 + 3] + q;
    *(float4*)(PTp + ((tc << 6) + r) * 512 + (tr << 6) + c4) = w;
  } else if (blk == 128) {
    // V1[c] = sum_j initp[j] * P[j][c], f64, split across 2 thread halves
    __shared__ double vred[512];
    int c = tid & 511, h = tid >> 9;
    const float* Ph = P + h * 256 * 512;
    const float* ih = initp + h * 256;
    double acc = 0.0;
    for (int j = 0; j < 256; ++j) acc += (double)ih[j] * (double)Ph[j * 512 + c];
    if (h == 0) vred[c] = acc;
    __syncthreads();
    if (h == 1) V1[c] = (float)(vred[c] + acc);
    if (tid < 512) INITROW[tid] = initp[tid];
  } else {
    if (tid < T_ - 1) {
      uint32_t a, b;
      step_key(ks0, ks1, tid, a, b);
      KEY0[tid] = a; KEY1[tid] = b;
    }
  }
}

// ---------------- GEMM tile (f64 MFMA, self-calibrating D layout) ----------------
__device__ __forceinline__ void gemm_tile(float* POW, int m, int y, int x,
                                          double (*As)[33], double (*Bs)[33],
                                          int tid, int gate) {
  if (y + 1 + m > gate) return;       // block-uniform
  const float* A  = POW + (size_t)y * POWSLOT;
  const float* Bm = POW + (size_t)(m - 1) * POWSLOT;
  float* C        = POW + (size_t)(y + m) * POWSLOT;
  int lane = tid & 63;
  int wv = tid >> 6;
  int wr = wv >> 1, wc = wv & 1;
  int q = lane >> 4, r16 = lane & 15;
  int r0 = (x >> 4) * 32;
  int c0 = (x & 15) * 32;
  f64x4 z = {0.0, 0.0, 0.0, 0.0};
  f64x4 d1 = __builtin_amdgcn_mfma_f64_16x16x4f64((double)r16, 1.0, z, 0, 0, 0);   // D=4i
  f64x4 d2 = __builtin_amdgcn_mfma_f64_16x16x4f64(1.0, (double)r16, z, 0, 0, 0);   // D=4j
  int ir[4], ic[4];
#pragma unroll
  for (int v = 0; v < 4; ++v) {
    ir[v] = (((int)d1[v]) >> 2) & 15;
    ic[v] = (((int)d2[v]) >> 2) & 15;
  }
  int sr = tid >> 3;
  int sk4 = (tid & 7) * 4;
  int ar = r0 + sr; if (ar > 512) ar = 512;
  f64x4 acc = {0.0, 0.0, 0.0, 0.0};
  float4 av = *(const float4*)(A + (size_t)ar * 512 + sk4);
  float4 bv = *(const float4*)(Bm + (size_t)sr * 512 + c0 + sk4);
  for (int kc = 0; kc < 512; kc += 32) {
    __syncthreads();                 // previous chunk's LDS reads done
    As[sk4 + 0][sr] = (double)av.x;
    As[sk4 + 1][sr] = (double)av.y;
    As[sk4 + 2][sr] = (double)av.z;
    As[sk4 + 3][sr] = (double)av.w;
    Bs[sr][sk4 + 0] = (double)bv.x;
    Bs[sr][sk4 + 1] = (double)bv.y;
    Bs[sr][sk4 + 2] = (double)bv.z;
    Bs[sr][sk4 + 3] = (double)bv.w;
    int kn = (kc + 32 < 512) ? kc + 32 : 480;  // clamped (last prefetch unused)
    av = *(const float4*)(A + (size_t)ar * 512 + kn + sk4);
    bv = *(const float4*)(Bm + (size_t)(kn + sr) * 512 + c0 + sk4);
    __syncthreads();
#pragma unroll
    for (int ks = 0; ks < 8; ++ks) {
      double a = As[ks * 4 + q][wr * 16 + r16];
      double b = Bs[ks * 4 + q][wc * 16 + r16];
      acc = __builtin_amdgcn_mfma_f64_16x16x4f64(a, b, acc, 0, 0, 0);
    }
  }
#pragma unroll
  for (int v = 0; v < 4; ++v) {
    int gr = r0 + wr * 16 + ir[v];
    int gc = c0 + wc * 16 + ic[v];
    if (gr < 513) C[(size_t)gr * 512 + gc] = (float)acc[v];
  }
}

// ---------------- Backward unit (bit-identical math to R11..R16) ----------------
__device__ __forceinline__ void bwd_unit(
    int run, int ci, int lane,
    const int* __restrict__ data, const float* wsF,
    const int* __restrict__ off, const float* PTp,
    const uint32_t* __restrict__ KEY0, const uint32_t* __restrict__ KEY1,
    int* __restrict__ out) {
  int b = run >> 20, ta = (run >> 10) & 1023, tb = run & 1023;
  const float* wsL = wsF + (lane << 3);
  const float* ptL = PTp + (lane << 3);
  int s = data[b * T_ + tb + 1];    // mask=1 or t=T-1: deterministic anchor
  uint32_t ebase = ((uint32_t)b << 11) | ((uint32_t)ci << 9) | ((uint32_t)(lane << 3));
  const int* offb = off + b * T_;
  int* outp = out + (((b << 2) | ci) * T_);
  for (int t = tb; t >= ta; --t) {
    int j = (T_ - 2) - t;
    uint32_t kj0 = KEY0[j], kj1 = KEY1[j];
    int o = offb[t];
    float4 m0 = *(const float4*)(wsL + o);
    float4 m1 = *(const float4*)(wsL + o + 4);
    const float* prow = ptL + ((size_t)s << 9);
    float4 p0 = *(const float4*)(prow);
    float4 p1 = *(const float4*)(prow + 4);
    float x0 = fmaf(m0.x, p0.x, 1e-20f) * gumbel_scale(rng_bits(kj0, kj1, ebase + 0u));
    float x1 = fmaf(m0.y, p0.y, 1e-20f) * gumbel_scale(rng_bits(kj0, kj1, ebase + 1u));
    float x2 = fmaf(m0.z, p0.z, 1e-20f) * gumbel_scale(rng_bits(kj0, kj1, ebase + 2u));
    float x3 = fmaf(m0.w, p0.w, 1e-20f) * gumbel_scale(rng_bits(kj0, kj1, ebase + 3u));
    float x4 = fmaf(m1.x, p1.x, 1e-20f) * gumbel_scale(rng_bits(kj0, kj1, ebase + 4u));
    float x5 = fmaf(m1.y, p1.y, 1e-20f) * gumbel_scale(rng_bits(kj0, kj1, ebase + 5u));
    float x6 = fmaf(m1.z, p1.z, 1e-20f) * gumbel_scale(rng_bits(kj0, kj1, ebase + 6u));
    float x7 = fmaf(m1.w, p1.w, 1e-20f) * gumbel_scale(rng_bits(kj0, kj1, ebase + 7u));
    float bv = x0; int bj = 0;
    if (x1 > bv) { bv = x1; bj = 1; }
    if (x2 > bv) { bv = x2; bj = 2; }
    if (x3 > bv) { bv = x3; bj = 3; }
    if (x4 > bv) { bv = x4; bj = 4; }
    if (x5 > bv) { bv = x5; bj = 5; }
    if (x6 > bv) { bv = x6; bj = 6; }
    if (x7 > bv) { bv = x7; bj = 7; }
    float wm = bv;
#pragma unroll
    for (int d = 1; d < 64; d <<= 1) wm = fmaxf(wm, __shfl_xor(wm, d));
    unsigned long long bal = __ballot(bv == wm);
    int wl = __ffsll(bal) - 1;       // lowest lane with the max = smallest k
    int jw = __shfl(bj, wl);
    s = (wl << 3) + jw;              // uniform across wave
    if (lane == 0) outp[t] = s;
  }
}

// ---------------- Fused main: GEMM chain + sort + backward, one dispatch ----------------
// flags[0..2] = per-stage done counters, flags[3] = sortCnt, flags[4] = stagesDone.
// Grid must equal 2048 (8 blocks/CU co-resident; spin-gating relies on it).
__global__ __launch_bounds__(256, 8) void fused_main(
    const int* __restrict__ data, const float* __restrict__ masks,
    float* wsF,
    const int* __restrict__ off,
    const uint32_t* __restrict__ KEY0, const uint32_t* __restrict__ KEY1,
    const int* __restrict__ runs, const int* __restrict__ runCount,
    const int* __restrict__ maxLdev, const int* __restrict__ hist,
    int* __restrict__ cursor, int* __restrict__ flags, int* __restrict__ runsSorted,
    int* __restrict__ out,
    int lmax, int a1, int a2, int c1, int c2, int c3) {
  __shared__ double As[32][33];
  __shared__ double Bs[32][33];
  int blk = blockIdx.x;
  int tid = threadIdx.x;
  float* POW = wsF;
  const float* PTp = wsF + (size_t)lmax * POWSLOT;

  // folded fill_out: deterministic outputs (observed t, and t = T-1)
  {
    int id = blk * 256 + tid;
    if (id < NCHAIN * T_) {
      int t = id & (T_ - 1);
      int b = id >> 12;
      if (t == T_ - 1 || masks[b * T_ + t] > 0.0f) out[id] = data[b * T_ + t];
    }
  }

  // ---- producer phases ----
  if (blk < GEMM_TILES * 2) {
    int gate = *maxLdev; if (gate > lmax) gate = lmax;
    // stage 1: m=1, tiles = 272*c1
    if (c1 > 0 && blk < GEMM_TILES * c1) {
      gemm_tile(POW, 1, blk / GEMM_TILES, blk % GEMM_TILES, As, Bs, tid, gate);
      __syncthreads();
      if (tid == 0) { if (add_arl(&flags[0], 1) + 1 == GEMM_TILES * c1) st_rel(&flags[4], 1); }
    }
    // stage 2: m=2
    if (c2 > 0 && blk < GEMM_TILES * c2) {
      if (tid == 0) { int g = 0; while (ld_acq(&flags[4]) < 1 && ++g < (1 << 22)) __builtin_amdgcn_s_sleep(8); }
      __syncthreads();
      gemm_tile(POW, 2, blk / GEMM_TILES, blk % GEMM_TILES, As, Bs, tid, gate);
      __syncthreads();
      if (tid == 0) { if (add_arl(&flags[1], 1) + 1 == GEMM_TILES * c2) st_rel(&flags[4], 2); }
    }
    // stage 3: m=4
    if (c3 > 0 && blk < GEMM_TILES * c3) {
      if (tid == 0) { int g = 0; while (ld_acq(&flags[4]) < 2 && ++g < (1 << 22)) __builtin_amdgcn_s_sleep(8); }
      __syncthreads();
      gemm_tile(POW, 4, blk / GEMM_TILES, blk % GEMM_TILES, As, Bs, tid, gate);
      __syncthreads();
      if (tid == 0) { if (add_arl(&flags[2], 1) + 1 == GEMM_TILES * c3) st_rel(&flags[4], 3); }
    }
  } else if (blk >= SORT_BASE && blk < SORT_BASE + SORT_BLOCKS) {
    // counting-sort scatter into runsSorted (descending step count);
    // LDS-staged ranks: ONE global atomicAdd per (block,bucket).
    int* ish = (int*)As;             // lhist2[64], gbase[64], sbase[64]
    int i = (blk - SORT_BASE) * 256 + tid;
    int total = *runCount; if (total > MAXRUNS) total = MAXRUNS;
    bool valid = i < total;
    if (tid < 64) ish[tid] = 0;
    __syncthreads();
    int r = 0, bkt = 0, lr = 0;
    if (valid) {
      r = runs[i];
      int ta = (r >> 10) & 1023, tb = r & 1023;
      int steps = tb - ta + 1;
      bkt = steps < 63 ? steps : 63;
      lr = atomicAdd(&ish[bkt], 1);
    }
    __syncthreads();
    if (tid < 64) {
      int c = ish[tid];
      ish[64 + tid] = c ? atomicAdd(&cursor[tid], c) : 0;
      int s = 0;
      for (int l = tid + 1; l < 64; ++l) s += hist[l];
      ish[128 + tid] = s;
    }
    __syncthreads();
    if (valid) runsSorted[ish[128 + bkt] + ish[64 + bkt] + lr] = r;
    __syncthreads();
    if (tid == 0) add_arl(&flags[3], 1);
  }

  // ---- backward phase (all blocks) ----
  int lane = tid & 63;
  int wv = tid >> 6;
  // remap so producer blocks (0..672) take the SHORTEST units
  int vblk = (blk + (MEGA_BLOCKS - 673)) & (MEGA_BLOCKS - 1);
  int wid = vblk * 4 + wv;
  {
    int g = 0;
    int sc = ld_acq(&flags[3]);
    while (__shfl(sc, 0) < SORT_BLOCKS && ++g < (1 << 22)) {
      __builtin_amdgcn_s_sleep(16);
      sc = ld_acq(&flags[3]);
    }
  }
  int total = *runCount;
  if (total > MAXRUNS) total = MAXRUNS;
  total <<= 2;                        // units = runs x 4 chains
  int sd = __shfl(ld_acq(&flags[4]), 0);
  unsigned skipped = 0;
  for (int k = 0; k * NWAVES < total; ++k) {
    int rr = k * NWAVES + ((k & 1) ? (NWAVES - 1 - wid) : wid);
    if (rr >= total) continue;
    int run = runsSorted[rr >> 2];
    int ta = (run >> 10) & 1023, tb = run & 1023;
    int len = tb - ta + 1;
    int nl = len > lmax ? lmax : len;
    int need = (nl <= 1) ? 0 : (nl <= a1) ? 1 : (nl <= a2) ? 2 : 3;
    if (need > sd) sd = __shfl(ld_acq(&flags[4]), 0);
    if (need > sd) { skipped |= (1u << k); continue; }
    bwd_unit(run, rr & 3, lane, data, wsF, off, PTp, KEY0, KEY1, out);
  }
  while (skipped) {
    int k = __builtin_ctz(skipped); skipped &= skipped - 1;
    int rr = k * NWAVES + ((k & 1) ? (NWAVES - 1 - wid) : wid);
    int run = runsSorted[rr >> 2];
    int ta = (run >> 10) & 1023, tb = run & 1023;
    int len = tb - ta + 1;
    int nl = len > lmax ? lmax : len;
    int need = (nl <= 1) ? 0 : (nl <= a1) ? 1 : (nl <= a2) ? 2 : 3;
    int g = 0;
    while (sd < need && ++g < (1 << 22)) {
      __builtin_amdgcn_s_sleep(16);
      sd = __shfl(ld_acq(&flags[4]), 0);
    }
    bwd_unit(run, rr & 3, lane, data, wsF, off, PTp, KEY0, KEY1, out);
  }
}

// ---------------- Launcher ----------------
extern "C" void kernel_launch(void* const* d_in, const int* in_sizes, int n_in,
                              void* d_out, int out_size, void* d_ws, size_t ws_size,
                              hipStream_t stream) {
  const int* data = (const int*)d_in[0];
  const float* masks = (const float*)d_in[1];
  const float* initp = (const float*)d_in[2];
  const float* P = (const float*)d_in[3];
  int* out = (int*)d_out;

  int lmax = LMAX_WANT;
  {
    long long fixed = 512LL * 512 + 512 + (long long)B_ * T_ + 2 * (T_ - 1)
                      + 2LL * MAXRUNS + 256;
    long long avail = (long long)(ws_size / 4) - fixed;
    long long fit = avail / POWSLOT;
    if (fit < lmax) lmax = (fit < 1) ? 1 : (int)fit;
  }
  float* wsF = (float*)d_ws;
  float* POW = wsF;
  float* PTp = wsF + (size_t)lmax * POWSLOT;
  float* INITROW = PTp + 512 * 512;
  int* off = (int*)(INITROW + 512);
  uint32_t* KEY0 = (uint32_t*)(off + B_ * T_);
  uint32_t* KEY1 = KEY0 + (T_ - 1);
  int* runs = (int*)(KEY1 + (T_ - 1));
  int* runCount = runs + MAXRUNS;     // header: [0] runCount, [1] maxLdev,
  int* maxLdev = runCount + 1;        // [2..65] hist, [66..129] cursor,
  int* hist = runCount + 2;           // [130..134] flags, [135..] runsSorted
  int* cursor = runCount + 66;
  int* flags = runCount + 130;
  int* runsSorted = runCount + 135;
  int initoff = lmax * POWSLOT + 512 * 512;   // INITROW position in floats

  // stage plan (doubling): lmax=6 -> c=(1,2,2); avail after stages = 2,4,6
  int c1 = 0, c2 = 0, c3 = 0;
  {
    int m = 1, cs[3] = {0, 0, 0}, i = 0;
    while (m < lmax && i < 3) { int c = lmax - m; if (c > m) c = m; cs[i++] = c; m += c; }
    c1 = cs[0]; c2 = cs[1]; c3 = cs[2];
  }
  int a1 = c1 ? 1 + c1 : 1;
  int a2 = c2 ? 2 + c2 : a1;

  uint32_t ks0, ks1;
#if JAX_PARTITIONABLE
  tf2x32(0u, 42u, 0u, 1u, ks0, ks1);
#else
  {
    uint32_t a0, b0, a1x, b1x;
    tf2x32(0u, 42u, 0u, 2u, a0, b0);
    tf2x32(0u, 42u, 1u, 3u, a1x, b1x);
    ks0 = b0; ks1 = b1x;
  }
#endif

  // zero header: runCount, maxLdev, hist, cursor, flags (135 ints; 140 w/ slack)
  hipMemsetAsync(runCount, 0, 140 * sizeof(int), stream);
  hipLaunchKernelGGL(setup_all, dim3(130), dim3(1024), 0, stream,
                     data, masks, P, initp, POW, PTp, INITROW, POW + 512 * 512,
                     off, lmax, initoff, runs, runCount, maxLdev, hist,
                     KEY0, KEY1, ks0, ks1);
  hipLaunchKernelGGL(fused_main, dim3(MEGA_BLOCKS), dim3(256), 0, stream,
                     data, masks, wsF, off, KEY0, KEY1, runs, runCount,
                     maxLdev, hist, cursor, flags, runsSorted, out,
                     lmax, a1, a2, c1, c2, c3);
}

// Round 7
// 312.351 us; speedup vs baseline: 7.1191x; 7.1191x over previous
//
#include <hip/hip_runtime.h>
#include <stdint.h>

// MarkovChain FFBS: B=64, T=1024, K=512, I=4
// R18 = R16 (proven 299.7us; R17's fused spin-gating reverted -- its
// polling loads were a same-address device-atomic storm, 2.2ms) plus
// two hint-level backward tweaks targeting the serial critical chain
// (longest run ~40-60 dependent steps; R16 occupancy 61% = drain tail):
//   1. s_setprio(1) while processing top-512-ranked (longest) units ->
//      critical waves get SIMD issue preference during the contended
//      phase (step ~6us fair-share -> ~1us).
//   2. chain-spreading: wave wid -> chain wid>>13, rank ((wid&8191)+
//      chain*1028)&8191 (+8192/round). A run's 4 chains land on blocks
//      ~1028 apart (!= 0 mod 256 -> different CUs), so critical chains
//      don't compete with their own copies. Coverage/LPT preserved.
// RNG keyed on (b,t,ci): mapping permutation does not change any value.
// Per-k backward values bit-identical to R11..R16 -> absmax 0.

#define JAX_PARTITIONABLE 1

#define B_ 64
#define T_ 1024
#define K_ 512
#define I_ 4
#define NCHAIN (B_ * I_)
#define POWSLOT (513 * 512)   // rows 0..511 = P^L, row 512 = init_p @ P^L
#define LMAX_WANT 6
#define MAXRUNS 32769
#define BWD_BLOCKS 8192
#define GEMM_BLOCKS (17 * 16)
#define SORT_BLOCKS 129       // ceil(MAXRUNS / 256)

typedef double f64x4 __attribute__((ext_vector_type(4)));

// ---------------- Threefry-2x32-20 (exact jax semantics) ----------------
__host__ __device__ inline void tf2x32(uint32_t k0, uint32_t k1, uint32_t c0, uint32_t c1,
                                       uint32_t& o0, uint32_t& o1) {
  uint32_t ks2 = k0 ^ k1 ^ 0x1BD11BDAu;
  uint32_t x0 = c0 + k0;
  uint32_t x1 = c1 + k1;
#define TFR(r) { x0 += x1; x1 = (x1 << (r)) | (x1 >> (32 - (r))); x1 ^= x0; }
  TFR(13) TFR(15) TFR(26) TFR(6)
  x0 += k1; x1 += ks2 + 1u;
  TFR(17) TFR(29) TFR(16) TFR(24)
  x0 += ks2; x1 += k0 + 2u;
  TFR(13) TFR(15) TFR(26) TFR(6)
  x0 += k0; x1 += k1 + 3u;
  TFR(17) TFR(29) TFR(16) TFR(24)
  x0 += k1; x1 += ks2 + 4u;
  TFR(13) TFR(15) TFR(26) TFR(6)
  x0 += ks2; x1 += k0 + 5u;
#undef TFR
  o0 = x0; o1 = x1;
}

__device__ inline uint32_t rng_bits(uint32_t kj0, uint32_t kj1, uint32_t e) {
#if JAX_PARTITIONABLE
  uint32_t a, b;
  tf2x32(kj0, kj1, 0u, e, a, b);
  return a ^ b;
#else
  const uint32_t HALF = (uint32_t)(NCHAIN * K_ / 2);
  uint32_t a, b;
  if (e < HALF) { tf2x32(kj0, kj1, e, e + HALF, a, b); return a; }
  else          { tf2x32(kj0, kj1, e - HALF, e, a, b); return b; }
#endif
}

// gumbel scale factor: G = -1/log(u) > 0, so that w*G is a monotone image of
// log(w) + (-log(-log u)). Branch-free log, <=2ulp RELATIVE everywhere
// (incl. u->1: e=0 path computes log(m) via exact m-1 and atanh series).
__device__ inline float gumbel_scale(uint32_t bits) {
  float f = __uint_as_float((bits >> 9) | 0x3F800000u) - 1.0f;
  float u = f + 1.17549435e-38f;            // u in [2^-126, 1)
  int iu = __float_as_int(u);
  float ef = (float)((iu >> 23) - 127);
  float m = __int_as_float((iu & 0x007fffff) | 0x3f800000);   // [1,2)
  int big = m > 1.41421356f;                // reduce to [~0.707, ~1.414)
  m = big ? m * 0.5f : m;
  ef = big ? ef + 1.0f : ef;
  float fm = m - 1.0f;                      // exact (Sterbenz)
  float r = fm * __builtin_amdgcn_rcpf(m + 1.0f);   // atanh arg, |r|<=0.172
  float r2 = r * r;
  float p = fmaf(r2, fmaf(r2, fmaf(r2, fmaf(r2, 0.11111111f, 0.14285715f),
                                   0.2f), 0.33333334f), 1.0f);
  float logu = fmaf(ef, 0.69314718f, (r + r) * p);  // < 0 strictly
  return -__builtin_amdgcn_rcpf(logu);
}

__device__ inline void step_key(uint32_t ks0, uint32_t ks1, int j, uint32_t& kj0, uint32_t& kj1) {
#if JAX_PARTITIONABLE
  tf2x32(ks0, ks1, 0u, (uint32_t)j, kj0, kj1);
#else
  const int N = T_ - 1;
  uint32_t o0, o1;
  int v = 2 * j;
  if (v < N) { tf2x32(ks0, ks1, (uint32_t)v, (uint32_t)(v + N), o0, o1); kj0 = o0; }
  else       { tf2x32(ks0, ks1, (uint32_t)(v - N), (uint32_t)v, o0, o1); kj0 = o1; }
  v = 2 * j + 1;
  if (v < N) { tf2x32(ks0, ks1, (uint32_t)v, (uint32_t)(v + N), o0, o1); kj1 = o0; }
  else       { tf2x32(ks0, ks1, (uint32_t)(v - N), (uint32_t)v, o0, o1); kj1 = o1; }
#endif
}

// ---------------- Merged setup: offsets scan + transpose + V1 + keys ----------------
// Header pre-zeroed via hipMemsetAsync.
// blocks 0..63   : per-b offsets scan, run extraction (LDS-aggregated hist/maxL)
// blocks 64..127 : 64x64 LDS-tiled transpose P -> PTp(+1/K), POW0 copy (same load)
// block 128      : V1 = initp @ P (f64, split-K over 2 halves) + INITROW copy
// block 129      : step keys
__global__ __launch_bounds__(1024) void setup_all(
    const int* __restrict__ data, const float* __restrict__ masks,
    const float* __restrict__ P, const float* __restrict__ initp,
    float* __restrict__ POW0, float* __restrict__ PTp,
    float* __restrict__ INITROW, float* __restrict__ V1,
    int* __restrict__ off, int lmax, int initoff,
    int* __restrict__ runs, int* __restrict__ runCount, int* __restrict__ maxLdev,
    int* __restrict__ hist,
    uint32_t* __restrict__ KEY0, uint32_t* __restrict__ KEY1,
    uint32_t ks0, uint32_t ks1) {
  int blk = blockIdx.x;
  int tid = threadIdx.x;
  if (blk < 64) {
    __shared__ int prevObs[1024];
    __shared__ int nextObs[1024];
    __shared__ int lhist[64];
    __shared__ int lmaxL;
    int b = blk;
    int t = tid;
    bool obs = masks[b * T_ + t] > 0.0f;
    prevObs[t] = obs ? t : -1;
    nextObs[t] = obs ? t : T_;
    if (t < 64) lhist[t] = 0;
    if (t == 0) lmaxL = 1;
    __syncthreads();
    for (int o = 1; o < 1024; o <<= 1) {
      int pv = (t >= o) ? prevObs[t - o] : -1;
      int nv = (t + o < 1024) ? nextObs[t + o] : T_;
      __syncthreads();
      if (pv > prevObs[t]) prevObs[t] = pv;
      if (nv < nextObs[t]) nextObs[t] = nv;
      __syncthreads();
    }
    int t0 = (t > 0) ? prevObs[t - 1] : -1;
    int idx = b * T_ + t;
    if (obs) off[idx] = -1;
    else if (t0 >= 0) {
      int L = t - t0; if (L > lmax) L = lmax;
      off[idx] = (L - 1) * POWSLOT + data[b * T_ + t0] * 512;
    } else if (t == 0) off[idx] = initoff;
    else {
      int L = t; if (L > lmax) L = lmax;
      off[idx] = (L - 1) * POWSLOT + 512 * 512;   // init-chain V row
    }
    if (!obs && t <= T_ - 2 && (t == 0 || masks[b * T_ + t - 1] > 0.0f)) {
      int te = nextObs[t] - 1; if (te > T_ - 2) te = T_ - 2;
      int r = atomicAdd(runCount, 1);   // uniform addr, +1 -> wave-coalesced
      if (r < MAXRUNS) {
        runs[r] = (b << 20) | (t << 10) | te;
        int steps = te - t + 1;
        int bkt = steps < 63 ? steps : 63;
        atomicAdd(&lhist[bkt], 1);                 // LDS atomic
        int maxL = (t == 0) ? te : (te - t + 1);
        if (maxL > 1) atomicMax(&lmaxL, maxL);     // LDS atomic
      }
    }
    __syncthreads();
    if (t < 64) {
      int c = lhist[t];
      if (c) atomicAdd(&hist[t], c);               // 64 distinct addresses
    }
    if (t == 0) {
      int v = lmaxL;
      if (v > 1) atomicMax(maxLdev, v);            // one per block
    }
  } else if (blk < 128) {
    // 64x64 tile transpose, both sides coalesced; POW0 copy reuses the load.
    __shared__ float Tls[64][65];
    int tt = blk - 64, tr = tt >> 3, tc = tt & 7;
    int r = tid >> 4, c4 = (tid & 15) << 2;
    int src = ((tr << 6) + r) * 512 + (tc << 6) + c4;
    float4 v = *(const float4*)(P + src);
    *(float4*)(POW0 + src) = v;
    Tls[c4 + 0][r] = v.x;
    Tls[c4 + 1][r] = v.y;
    Tls[c4 + 2][r] = v.z;
    Tls[c4 + 3][r] = v.w;
    __syncthreads();
    const float q = 0.001953125f;   // + 1/K, bit-identical to inline add
    float4 w;
    w.x = Tls[r][c4 + 0] + q;
    w.y = Tls[r][c4 + 1] + q;
    w.z = Tls[r][c4 + 2] + q;
    w.w = Tls[r][c4 + 3] + q;
    *(float4*)(PTp + ((tc << 6) + r) * 512 + (tr << 6) + c4) = w;
  } else if (blk == 128) {
    // V1[c] = sum_j initp[j] * P[j][c], f64, split across 2 thread halves
    __shared__ double vred[512];
    int c = tid & 511, h = tid >> 9;
    const float* Ph = P + h * 256 * 512;
    const float* ih = initp + h * 256;
    double acc = 0.0;
    for (int j = 0; j < 256; ++j) acc += (double)ih[j] * (double)Ph[j * 512 + c];
    if (h == 0) vred[c] = acc;
    __syncthreads();
    if (h == 1) V1[c] = (float)(vred[c] + acc);
    if (tid < 512) INITROW[tid] = initp[tid];
  } else {
    if (tid < T_ - 1) {
      uint32_t a, b;
      step_key(ks0, ks1, tid, a, b);
      KEY0[tid] = a; KEY1[tid] = b;
    }
  }
}

// ---------------- Power GEMM via f64 MFMA (self-calibrating D layout) ----------------
// 32x32 block tile, 4 waves (2x2 of 16x16), Kc=32 chunks, reg-prefetch.
// First launch carries SORT_BLOCKS extra blocks (x >= GEMM_BLOCKS, y == 0)
// that counting-sort-scatter runs into runsSorted (descending step count).
// Scatter uses LDS-staged ranks: one global atomicAdd per (block,bucket).
__global__ __launch_bounds__(256) void power_gemm_mfma(
    float* __restrict__ POW, int m, int lmax, const int* __restrict__ maxLdev,
    int sortN, const int* __restrict__ runs, const int* __restrict__ runCount,
    const int* __restrict__ hist, int* __restrict__ cursor,
    int* __restrict__ runsSorted) {
  if (blockIdx.x >= GEMM_BLOCKS) {
    if (sortN && blockIdx.y == 0) {
      __shared__ int lhist2[64];
      __shared__ int gbase[64];
      __shared__ int sbase[64];
      int tid = threadIdx.x;
      int i = (blockIdx.x - GEMM_BLOCKS) * 256 + tid;
      int total = *runCount; if (total > MAXRUNS) total = MAXRUNS;
      bool valid = i < total;
      if (tid < 64) lhist2[tid] = 0;
      __syncthreads();
      int r = 0, bkt = 0, lr = 0;
      if (valid) {
        r = runs[i];
        int ta = (r >> 10) & 1023, tb = r & 1023;
        int steps = tb - ta + 1;
        bkt = steps < 63 ? steps : 63;
        lr = atomicAdd(&lhist2[bkt], 1);         // LDS: rank within block
      }
      __syncthreads();
      if (tid < 64) {
        int c = lhist2[tid];
        gbase[tid] = c ? atomicAdd(&cursor[tid], c) : 0;   // 1 per (block,bucket)
        int s = 0;
        for (int l = tid + 1; l < 64; ++l) s += hist[l];   // suffix base (desc order)
        sbase[tid] = s;
      }
      __syncthreads();
      if (valid) runsSorted[sbase[bkt] + gbase[bkt] + lr] = r;
    }
    return;
  }
  int y = blockIdx.y;
  {
    int gate = *maxLdev; if (gate > lmax) gate = lmax;
    if (y + 1 + m > gate) return;
  }
  const float* A  = POW + (size_t)y * POWSLOT;
  const float* Bm = POW + (size_t)(m - 1) * POWSLOT;
  float* C        = POW + (size_t)(y + m) * POWSLOT;
  __shared__ double As[32][33];   // [k][r]
  __shared__ double Bs[32][33];   // [k][c]
  int tid = threadIdx.x;
  int lane = tid & 63;
  int wv = tid >> 6;              // wave 0..3
  int wr = wv >> 1, wc = wv & 1;  // 2x2 wave grid
  int q = lane >> 4, r16 = lane & 15;
  int r0 = (blockIdx.x >> 4) * 32;   // 17 row tiles cover 513 rows
  int c0 = (blockIdx.x & 15) * 32;   // 16 col tiles

  // --- calibrate D mapping: (lane,reg) -> (i,j). Exact integer probes. ---
  f64x4 z = {0.0, 0.0, 0.0, 0.0};
  f64x4 d1 = __builtin_amdgcn_mfma_f64_16x16x4f64((double)r16, 1.0, z, 0, 0, 0);   // D=4i
  f64x4 d2 = __builtin_amdgcn_mfma_f64_16x16x4f64(1.0, (double)r16, z, 0, 0, 0);   // D=4j
  int ir[4], ic[4];
#pragma unroll
  for (int v = 0; v < 4; ++v) {
    ir[v] = (((int)d1[v]) >> 2) & 15;
    ic[v] = (((int)d2[v]) >> 2) & 15;
  }

  // staging: thread loads 4 consecutive f32 of an A row and a B row.
  int sr = tid >> 3;                 // 0..31
  int sk4 = (tid & 7) * 4;           // 0,4,..,28
  int ar = r0 + sr; if (ar > 512) ar = 512;   // clamp (stores guarded)

  f64x4 acc = {0.0, 0.0, 0.0, 0.0};
  float4 av = *(const float4*)(A + (size_t)ar * 512 + sk4);
  float4 bv = *(const float4*)(Bm + (size_t)sr * 512 + c0 + sk4);
  for (int kc = 0; kc < 512; kc += 32) {
    __syncthreads();                 // previous chunk's LDS reads done
    As[sk4 + 0][sr] = (double)av.x;
    As[sk4 + 1][sr] = (double)av.y;
    As[sk4 + 2][sr] = (double)av.z;
    As[sk4 + 3][sr] = (double)av.w;
    Bs[sr][sk4 + 0] = (double)bv.x;
    Bs[sr][sk4 + 1] = (double)bv.y;
    Bs[sr][sk4 + 2] = (double)bv.z;
    Bs[sr][sk4 + 3] = (double)bv.w;
    int kn = (kc + 32 < 512) ? kc + 32 : 480;  // clamped (last prefetch unused)
    av = *(const float4*)(A + (size_t)ar * 512 + kn + sk4);
    bv = *(const float4*)(Bm + (size_t)(kn + sr) * 512 + c0 + sk4);
    __syncthreads();
#pragma unroll
    for (int ks = 0; ks < 8; ++ks) {
      double a = As[ks * 4 + q][wr * 16 + r16];
      double b = Bs[ks * 4 + q][wc * 16 + r16];
      acc = __builtin_amdgcn_mfma_f64_16x16x4f64(a, b, acc, 0, 0, 0);
    }
  }
#pragma unroll
  for (int v = 0; v < 4; ++v) {
    int gr = r0 + wr * 16 + ir[v];
    int gc = c0 + wc * 16 + ic[v];
    if (gr < 513) C[(size_t)gr * 512 + gc] = (float)acc[v];
  }
}

// ---------------- Backward sampling: wave-per-(run,chain), LPT + spread ----------------
// Lane l owns k = 8l..8l+7 (float4x2 msg/ptp loads). Argmax via fmaxf
// butterfly + ballot (lowest lane with max = smallest k; within-lane scan
// keeps smallest j). Per-k values bit-identical to R11..R16.
// Mapping: chain = wid>>13; rank = ((wid&8191)+chain*1028)&8191 (+8192/round)
// over length-DESCENDING runsSorted. Each run's 4 chains land on blocks
// ~1028 apart (different CUs); each chain band covers all ranks (rotation).
// s_setprio(1) on top-512 ranks: critical serial chains get issue priority.
__global__ __launch_bounds__(256) void backward_run(
    const int* __restrict__ data, const float* __restrict__ masks,
    const float* __restrict__ wsF, const int* __restrict__ off,
    const float* __restrict__ PTp,
    const uint32_t* __restrict__ KEY0, const uint32_t* __restrict__ KEY1,
    const int* __restrict__ runs, const int* __restrict__ runCount,
    int* __restrict__ out) {
  // folded fill_out: deterministic outputs (observed t, and t = T-1)
  {
    int id = blockIdx.x * 256 + threadIdx.x;
    if (id < NCHAIN * T_) {
      int t = id & (T_ - 1);
      int b = id >> 12;               // id>>10 = chain, chain>>2 = b
      if (t == T_ - 1 || masks[b * T_ + t] > 0.0f) out[id] = data[b * T_ + t];
    }
  }
  int lane = threadIdx.x & 63;
  int wv = threadIdx.x >> 6;
  int wid = blockIdx.x * 4 + wv;       // 0..32767
  int ci = wid >> 13;                  // chain 0..3
  int rbase = ((wid & 8191) + ci * 1028) & 8191;
  int nruns = *runCount;
  if (nruns > MAXRUNS) nruns = MAXRUNS;
  const float* wsL = wsF + (lane << 3);
  const float* ptL = PTp + (lane << 3);
  for (int r = rbase; r < nruns; r += 8192) {
    bool pri = (r < 512);
    if (pri) __builtin_amdgcn_s_setprio(1);
    int run = runs[r];
    int b = run >> 20, ta = (run >> 10) & 1023, tb = run & 1023;
    int s = data[b * T_ + tb + 1];    // mask=1 or t=T-1: deterministic anchor
    uint32_t ebase = ((uint32_t)b << 11) | ((uint32_t)ci << 9) | ((uint32_t)(lane << 3));
    const int* offb = off + b * T_;
    int* outp = out + (((b << 2) | ci) * T_);
    for (int t = tb; t >= ta; --t) {
      int j = (T_ - 2) - t;
      uint32_t kj0 = KEY0[j], kj1 = KEY1[j];
      int o = offb[t];
      float4 m0 = *(const float4*)(wsL + o);
      float4 m1 = *(const float4*)(wsL + o + 4);
      const float* prow = ptL + ((size_t)s << 9);
      float4 p0 = *(const float4*)(prow);
      float4 p1 = *(const float4*)(prow + 4);
      float x0 = fmaf(m0.x, p0.x, 1e-20f) * gumbel_scale(rng_bits(kj0, kj1, ebase + 0u));
      float x1 = fmaf(m0.y, p0.y, 1e-20f) * gumbel_scale(rng_bits(kj0, kj1, ebase + 1u));
      float x2 = fmaf(m0.z, p0.z, 1e-20f) * gumbel_scale(rng_bits(kj0, kj1, ebase + 2u));
      float x3 = fmaf(m0.w, p0.w, 1e-20f) * gumbel_scale(rng_bits(kj0, kj1, ebase + 3u));
      float x4 = fmaf(m1.x, p1.x, 1e-20f) * gumbel_scale(rng_bits(kj0, kj1, ebase + 4u));
      float x5 = fmaf(m1.y, p1.y, 1e-20f) * gumbel_scale(rng_bits(kj0, kj1, ebase + 5u));
      float x6 = fmaf(m1.z, p1.z, 1e-20f) * gumbel_scale(rng_bits(kj0, kj1, ebase + 6u));
      float x7 = fmaf(m1.w, p1.w, 1e-20f) * gumbel_scale(rng_bits(kj0, kj1, ebase + 7u));
      // local argmax, strict > keeps smallest j on ties
      float bv = x0; int bj = 0;
      if (x1 > bv) { bv = x1; bj = 1; }
      if (x2 > bv) { bv = x2; bj = 2; }
      if (x3 > bv) { bv = x3; bj = 3; }
      if (x4 > bv) { bv = x4; bj = 4; }
      if (x5 > bv) { bv = x5; bj = 5; }
      if (x6 > bv) { bv = x6; bj = 6; }
      if (x7 > bv) { bv = x7; bj = 7; }
      // wave max (butterfly -> all lanes hold identical max)
      float wm = bv;
#pragma unroll
      for (int d = 1; d < 64; d <<= 1) wm = fmaxf(wm, __shfl_xor(wm, d));
      unsigned long long bal = __ballot(bv == wm);
      int wl = __ffsll(bal) - 1;       // lowest lane with the max = smallest k
      int jw = __shfl(bj, wl);
      s = (wl << 3) + jw;              // uniform across wave
      if (lane == 0) outp[t] = s;
    }
    if (pri) __builtin_amdgcn_s_setprio(0);
  }
}

// ---------------- Launcher ----------------
extern "C" void kernel_launch(void* const* d_in, const int* in_sizes, int n_in,
                              void* d_out, int out_size, void* d_ws, size_t ws_size,
                              hipStream_t stream) {
  const int* data = (const int*)d_in[0];
  const float* masks = (const float*)d_in[1];
  const float* initp = (const float*)d_in[2];
  const float* P = (const float*)d_in[3];
  int* out = (int*)d_out;

  int lmax = LMAX_WANT;
  {
    long long fixed = 512LL * 512 + 512 + (long long)B_ * T_ + 2 * (T_ - 1)
                      + 2LL * MAXRUNS + 256;
    long long avail = (long long)(ws_size / 4) - fixed;
    long long fit = avail / POWSLOT;
    if (fit < lmax) lmax = (fit < 1) ? 1 : (int)fit;
  }
  float* wsF = (float*)d_ws;
  float* POW = wsF;
  float* PTp = wsF + (size_t)lmax * POWSLOT;
  float* INITROW = PTp + 512 * 512;
  int* off = (int*)(INITROW + 512);
  uint32_t* KEY0 = (uint32_t*)(off + B_ * T_);
  uint32_t* KEY1 = KEY0 + (T_ - 1);
  int* runs = (int*)(KEY1 + (T_ - 1));
  int* runCount = runs + MAXRUNS;
  int* maxLdev = runCount + 1;
  int* histcur = runCount + 2;        // hist[64] then cursor[64]
  int* hist = histcur;
  int* cursor = histcur + 64;
  int* runsSorted = histcur + 128;
  int initoff = lmax * POWSLOT + 512 * 512;   // INITROW position in floats

  uint32_t ks0, ks1;
#if JAX_PARTITIONABLE
  tf2x32(0u, 42u, 0u, 1u, ks0, ks1);
#else
  {
    uint32_t a0, b0, a1, b1;
    tf2x32(0u, 42u, 0u, 2u, a0, b0);
    tf2x32(0u, 42u, 1u, 3u, a1, b1);
    ks0 = b0; ks1 = b1;
  }
#endif

  // zero header: runCount, maxLdev, hist[64], cursor[64] (130 ints).
  // maxLdev=0 is equivalent to 1 here (only values >1 are ever atomicMax'd).
  hipMemsetAsync(runCount, 0, 130 * sizeof(int), stream);
  hipLaunchKernelGGL(setup_all, dim3(130), dim3(1024), 0, stream,
                     data, masks, P, initp, POW, PTp, INITROW, POW + 512 * 512,
                     off, lmax, initoff, runs, runCount, maxLdev, hist,
                     KEY0, KEY1, ks0, ks1);
  int m = 1, first = 1;
  while (m < lmax) {
    int count = lmax - m; if (count > m) count = m;
    hipLaunchKernelGGL(power_gemm_mfma,
                       dim3(GEMM_BLOCKS + (first ? SORT_BLOCKS : 0), count), dim3(256), 0, stream,
                       POW, m, lmax, maxLdev,
                       first, runs, runCount, hist, cursor, runsSorted);
    first = 0;
    m += count;
  }
  if (first) {
    // lmax == 1: GEMM blocks gate off in-kernel; sort blocks still run.
    hipLaunchKernelGGL(power_gemm_mfma,
                       dim3(GEMM_BLOCKS + SORT_BLOCKS, 1), dim3(256), 0, stream,
                       POW, 1, lmax, maxLdev,
                       1, runs, runCount, hist, cursor, runsSorted);
  }
  hipLaunchKernelGGL(backward_run, dim3(BWD_BLOCKS), dim3(256), 0, stream,
                     data, masks, wsF, off, PTp, KEY0, KEY1, runsSorted, runCount, out);
}